// Round 14
// baseline (198.382 us; speedup 1.0000x reference)
//
#include <hip/hip_runtime.h>
#include <hip/hip_bf16.h>

#define B_  4
#define L_  2048
#define D_  512
#define H_  8
#define HD_ 64
#define M_  (B_ * L_)   // 8192

typedef __bf16 bf16;
typedef __attribute__((ext_vector_type(8)))  __bf16 bf16x8;
typedef __attribute__((ext_vector_type(4)))  __bf16 bf16x4;
typedef __attribute__((ext_vector_type(16))) float  f32x16;

__device__ __forceinline__ f32x16 mfma32(bf16x8 a, bf16x8 b, f32x16 c) {
    return __builtin_amdgcn_mfma_f32_32x32x16_bf16(a, b, c, 0, 0, 0);
}

// ---- projections: relu(X @ W^T + b) (*postmul) ----
// ROUND-14: pack_w ELIMINATED.  Budget accounting (R13: attn 49 + qkv ~46
// + o ~40 + pack_w 4 + ~45us of launch gaps = 191.5) says launch count is
// the cheapest lever (~10us/launch, matches R8->R10's -4us for one launch).
// W has the same orientation as X (X@W^T needs W[n][k], k contiguous), so
// the R10-proven fused fp32->panel LDS transpose (stA) applies verbatim to
// the B path: weights are packed on the fly inside both proj kernels.
// 3 launches total: proj_qkv -> attn -> proj_o.
// Output modes: 0 bf16 [B,H,L,HD]; 1 K-panels [BH][8][L][8]; 2 fp32
// [M,512]; 3 V-panels [BH][256][64][8] PI-swizzled.
struct PJob {
    const bf16* X; const float* Xf; const float* Wf; const float* bias;
    void* out; float postmul; int mode;
};

__device__ __forceinline__ void barrier_lds_only()
{
    // Drain LDS ops so other waves see our ds_writes, but leave global
    // loads (vmcnt) in flight across the barrier.
    asm volatile("s_waitcnt lgkmcnt(0)" ::: "memory");
    __builtin_amdgcn_s_barrier();
}

__device__ __forceinline__ void proj_epilogue_elem(const PJob& jb, int row,
                                                   int col, float v)
{
    const int mode = jb.mode;
    if (mode == 2) {
        ((float*)jb.out)[(size_t)row * D_ + col] = v;
    } else {
        v *= jb.postmul;
        const int b = row >> 11, l = row & (L_ - 1);
        const int h = col >> 6,  hd = col & (HD_ - 1);
        const int bh = b * H_ + h;
        size_t idx;
        if (mode == 0) {
            idx = ((size_t)bh * L_ + l) * HD_ + hd;
        } else if (mode == 1) {       // K panels [bh][hd>>3][l][hd&7]
            idx = (((size_t)bh * 8 + (hd >> 3)) * L_ + l) * 8 + (hd & 7);
        } else {                      // mode 3: V panels, PI-swizzled j
            const int swzl = (l & ~15) | (l & 3) | ((l & 4) << 1) | ((l & 8) >> 1);
            idx = (((size_t)bh * 256 + (swzl >> 3)) * 64 + hd) * 8 + (swzl & 7);
        }
        ((bf16*)jb.out)[idx] = (bf16)v;
    }
}

// qkv: 128x128 tile, k-step 32, fused fp32 transpose for BOTH A and B,
// counted-vmcnt barrier.  grid (64, 4, 3) = 768 blocks = 3/CU (resident).
// 128x32 fp32 tile -> panel LDS mapping (hardware-verified R10-R13 as stA):
//   thread loads T[m0+r][k0+c4*4] (r=idx>>3, c4=idx&7; coalesced 128B);
//   dest slot fs=((c4>>2)<<2)|(r>>5), ln=(r&31)|(((c4>>1)&1)<<5),
//   byte (c4&1)*4.  Identity: k = k0+(c4>>2)*16+((c4>>1)&1)*8+(c4&1)*4+j.
__global__ __launch_bounds__(256, 3) void proj_qkv_kernel(PJob j0, PJob j1, PJob j2)
{
    const PJob jb = (blockIdx.z == 0) ? j0 : (blockIdx.z == 1) ? j1 : j2;
    const int lane = threadIdx.x & 63;
    const int w    = threadIdx.x >> 6;
    const int l31  = lane & 31;
    const int hi   = lane >> 5;
    const int m0 = blockIdx.x * 128;
    const int n0 = blockIdx.y * 128;
    const int mh = w & 1;
    const int nh = w >> 1;

    __shared__ __align__(16) bf16 Ab[2][8][64][8];   // 2 x 8 KB
    __shared__ __align__(16) bf16 Bb[2][8][64][8];   // 2 x 8 KB

    f32x16 acc[2][2];
#pragma unroll
    for (int mi = 0; mi < 2; mi++)
#pragma unroll
        for (int ni = 0; ni < 2; ni++)
#pragma unroll
            for (int r = 0; r < 16; r++) acc[mi][ni][r] = 0.0f;

    float4 rT[2][4], rTB[2][4];

    auto ldT = [&](float4 (&rr)[2][4], const float* src, int base, int s, int k0) {
#pragma unroll
        for (int rep = 0; rep < 4; rep++) {
            const int idx = rep * 256 + (int)threadIdx.x;
            rr[s][rep] = *(const float4*)(src + (size_t)(base + (idx >> 3)) * 512
                                          + k0 + (idx & 7) * 4);
        }
    };
    auto stT = [&](const float4 (&rr)[2][4], bf16 (*dst)[64][8], int s) {
#pragma unroll
        for (int rep = 0; rep < 4; rep++) {
            const int idx = rep * 256 + (int)threadIdx.x;
            const int r = idx >> 3, c4 = idx & 7;
            const float4 f = rr[s][rep];
            bf16x4 v; v[0] = (bf16)f.x; v[1] = (bf16)f.y;
            v[2] = (bf16)f.z; v[3] = (bf16)f.w;
            const int fs = ((c4 >> 2) << 2) | (r >> 5);
            const int ln = (r & 31) | (((c4 >> 1) & 1) << 5);
            *(bf16x4*)(&dst[fs][ln][(c4 & 1) * 4]) = v;
        }
    };

    // prologue: k0 -> LDS0; k32 -> set1; k64 -> set0.
    ldT(rT, jb.Xf, m0, 0, 0);  ldT(rTB, jb.Wf, n0, 0, 0);
    stT(rT, Ab[0], 0);         stT(rTB, Bb[0], 0);
    ldT(rT, jb.Xf, m0, 1, 32); ldT(rTB, jb.Wf, n0, 1, 32);
    ldT(rT, jb.Xf, m0, 0, 64); ldT(rTB, jb.Wf, n0, 0, 64);
    __syncthreads();

#pragma unroll
    for (int it = 0; it < 16; it++) {
        const int cur = it & 1;
#pragma unroll
        for (int ks = 0; ks < 2; ks++) {
            const bf16x8 a0 = *(const bf16x8*)(&Ab[cur][ks * 4 + mh * 2 + 0][lane][0]);
            const bf16x8 a1 = *(const bf16x8*)(&Ab[cur][ks * 4 + mh * 2 + 1][lane][0]);
            const bf16x8 b0 = *(const bf16x8*)(&Bb[cur][ks * 4 + nh * 2 + 0][lane][0]);
            const bf16x8 b1 = *(const bf16x8*)(&Bb[cur][ks * 4 + nh * 2 + 1][lane][0]);
            acc[0][0] = mfma32(a0, b0, acc[0][0]);
            acc[0][1] = mfma32(a0, b1, acc[0][1]);
            acc[1][0] = mfma32(a1, b0, acc[1][0]);
            acc[1][1] = mfma32(a1, b1, acc[1][1]);
        }
        if (it < 15) {
            const int s = (it + 1) & 1;          // set holding k_{it+1}
            stT(rT, Ab[1 - cur], s);
            stT(rTB, Bb[1 - cur], s);
            if (it < 13) {                       // refill set with k_{it+3}
                ldT(rT, jb.Xf, m0, s, (it + 3) * 32);
                ldT(rTB, jb.Wf, n0, s, (it + 3) * 32);
            }
            barrier_lds_only();                  // counted vmcnt rides
        }
    }

#pragma unroll
    for (int ni = 0; ni < 2; ni++) {
        const int col = n0 + (nh * 2 + ni) * 32 + l31;
        const float bn = jb.bias[col];
#pragma unroll
        for (int mi = 0; mi < 2; mi++)
#pragma unroll
            for (int r = 0; r < 16; r++) {
                const int row = m0 + (mh * 2 + mi) * 32 + (r & 3) + 8 * (r >> 2) + 4 * hi;
                proj_epilogue_elem(jb, row, col, fmaxf(acc[mi][ni][r] + bn, 0.0f));
            }
    }
}

// o-proj: R13 structure (128x64 tile, k-step 64, 3-deep A panel prefetch,
// __syncthreads, grid (64,8) = 512 blocks = 2/CU) with the B path fused
// from fp32 W.  64x64 fp32 tile -> panel mapping (same algebra as stA,
// re-derived for the 64-col ldB slot layout f=(koct_local&~1)|(r>>5)):
//   r=idx>>4, c4=idx&15; fs=((c4>>2)<<1)|(r>>5),
//   ln=(r&31)|(((c4>>1)&1)<<5), byte (c4&1)*4.
__global__ __launch_bounds__(256, 3) void proj_o_kernel(PJob jb)
{
    const int w    = threadIdx.x >> 6;
    const int lane = threadIdx.x & 63;
    const int l31  = lane & 31;
    const int hi   = lane >> 5;
    const int m0 = blockIdx.x * 128;
    const int n0 = blockIdx.y * 64;
    const int mh = w & 1;
    const int nh = w >> 1;

    __shared__ __align__(16) bf16 Ab[2][16][64][8];   // 32 KB
    __shared__ __align__(16) bf16 Bb[2][8][64][8];    // 16 KB

    f32x16 acc[2];
#pragma unroll
    for (int mi = 0; mi < 2; mi++)
#pragma unroll
        for (int r = 0; r < 16; r++) acc[mi][r] = 0.0f;

    auto ldA = [&](int f, int k0) -> bf16x8 {
        return *(const bf16x8*)(jb.X + ((size_t)((k0 >> 3) + (f >> 2) * 2 + hi) * M_
                                        + m0 + (f & 3) * 32 + l31) * 8);
    };

    bf16x8 rA[3][4];
    float4 rTB[2][4];

    auto ldTB = [&](int s, int k0) {            // fp32 B: 64 rows x 64 k
#pragma unroll
        for (int rep = 0; rep < 4; rep++) {
            const int idx = rep * 256 + (int)threadIdx.x;
            rTB[s][rep] = *(const float4*)(jb.Wf + (size_t)(n0 + (idx >> 4)) * 512
                                           + k0 + (idx & 15) * 4);
        }
    };
    auto stTB = [&](int s, int buf) {
#pragma unroll
        for (int rep = 0; rep < 4; rep++) {
            const int idx = rep * 256 + (int)threadIdx.x;
            const int r = idx >> 4, c4 = idx & 15;
            const float4 f = rTB[s][rep];
            bf16x4 v; v[0] = (bf16)f.x; v[1] = (bf16)f.y;
            v[2] = (bf16)f.z; v[3] = (bf16)f.w;
            const int fs = ((c4 >> 2) << 1) | (r >> 5);
            const int ln = (r & 31) | (((c4 >> 1) & 1) << 5);
            *(bf16x4*)(&Bb[buf][fs][ln][(c4 & 1) * 4]) = v;
        }
    };

    // prologue: A 3-deep panels; B 2-deep fp32 (k0 -> LDS0; k64 -> set1;
    // k128 -> set0).
#pragma unroll
    for (int i = 0; i < 4; i++) rA[0][i] = ldA(w * 4 + i, 0);
    ldTB(0, 0);
#pragma unroll
    for (int i = 0; i < 4; i++) *(bf16x8*)(&Ab[0][w * 4 + i][lane][0]) = rA[0][i];
    stTB(0, 0);
#pragma unroll
    for (int s = 1; s < 3; s++)
#pragma unroll
        for (int i = 0; i < 4; i++) rA[s][i] = ldA(w * 4 + i, s * 64);
    ldTB(1, 64);
    ldTB(0, 128);
    __syncthreads();

#pragma unroll
    for (int it = 0; it < 8; it++) {
        const int cur = it & 1;
        if (it < 5) {
            const int s = it % 3, kn = (it + 3) * 64;
#pragma unroll
            for (int i = 0; i < 4; i++) rA[s][i] = ldA(w * 4 + i, kn);
        }
#pragma unroll
        for (int ks = 0; ks < 4; ks++) {
            const bf16x8 bfr = *(const bf16x8*)(&Bb[cur][ks * 2 + nh][lane][0]);
#pragma unroll
            for (int mi = 0; mi < 2; mi++) {
                const bf16x8 afr = *(const bf16x8*)(&Ab[cur][ks * 4 + mh * 2 + mi][lane][0]);
                acc[mi] = mfma32(afr, bfr, acc[mi]);
            }
        }
        if (it < 7) {
            const int sA = (it + 1) % 3;
#pragma unroll
            for (int i = 0; i < 4; i++) *(bf16x8*)(&Ab[1 - cur][w * 4 + i][lane][0]) = rA[sA][i];
            const int sB = (it + 1) & 1;         // set holding k_{it+1}
            stTB(sB, 1 - cur);
            if (it < 5) ldTB(sB, (it + 3) * 64); // refill with k_{it+3}
            __syncthreads();
        }
    }

    const int col = n0 + nh * 32 + l31;
    const float bn = jb.bias[col];
#pragma unroll
    for (int mi = 0; mi < 2; mi++)
#pragma unroll
        for (int r = 0; r < 16; r++) {
            const int row = m0 + (mh * 2 + mi) * 32 + (r & 3) + 8 * (r >> 2) + 4 * hi;
            proj_epilogue_elem(jb, row, col, fmaxf(acc[mi][r] + bn, 0.0f));
        }
}

// ---- flash attention, max-free (post-ReLU q,k => scores >= 0) ----
// EXACT round-0 structure + XCD-chunked swizzle (R7-R13: 48.1-49.4 us,
// 100 VGPR, FETCH 12.3 MB).  DO NOT TOUCH: rounds 2-5 proved every TLP/ILP
// restructuring crosses a register-class boundary and spills; R1 proved
// removing its barrier does NOT help (loads are L2-hot; V-sharing wins).
__global__ __launch_bounds__(128, 2) void attn_kernel(
    const bf16* __restrict__ qh, const bf16* __restrict__ Kp,
    const bf16* __restrict__ Vp, bf16* __restrict__ Op)
{
    const int w    = threadIdx.x >> 6;   // 0..1
    const int lane = threadIdx.x & 63;
    const int l31  = lane & 31;
    const int hi   = lane >> 5;

    const int lin  = blockIdx.x + (blockIdx.y << 5);   // grid (32,32)
    const int xcd  = lin & 7;
    const int slot = lin >> 3;                          // 0..127 within XCD
    const int bh   = (xcd << 2) + (slot >> 5);          // 4 bh per XCD
    const int qb   = (slot & 31) * 64 + w * 32;

    const bf16* Q   = qh + (size_t)bh * L_ * HD_;
    const bf16* Kpb = Kp + (size_t)bh * 8 * L_ * 8;
    const bf16* Vpb = Vp + (size_t)bh * 256 * 64 * 8;

    __shared__ __align__(16) bf16 Vb[2][8][64][8];   // 16 KB

    bf16x8 qf[4];
#pragma unroll
    for (int ks = 0; ks < 4; ks++)
        qf[ks] = *(const bf16x8*)(Q + (size_t)(qb + l31) * HD_ + ks * 16 + hi * 8);

    f32x16 zz;
#pragma unroll
    for (int r = 0; r < 16; r++) zz[r] = 0.0f;
    f32x16 o0 = zz, o1 = zz, lacc = zz;
    bf16x8 ones;
#pragma unroll
    for (int u = 0; u < 8; u++) ones[u] = (bf16)1.0f;

    auto ldK = [&](int f, int t) -> bf16x8 {   // f: ks=f>>1, jt=f&1
        return *(const bf16x8*)(Kpb + ((size_t)((f >> 1) * 2 + hi) * L_
                                       + t * 64 + (f & 1) * 32 + l31) * 8);
    };
    auto ldV = [&](int f, int t) -> bf16x8 {   // f: ksj=f>>1, hdf=f&1
        return *(const bf16x8*)(Vpb + ((size_t)(t * 8 + (f >> 1) * 2 + hi) * 64
                                       + (f & 1) * 32 + l31) * 8);
    };

    bf16x8 kr[8], vr[2][4];
#pragma unroll
    for (int i = 0; i < 4; i++) vr[0][i] = ldV(w * 4 + i, 0);
#pragma unroll
    for (int i = 0; i < 4; i++) *(bf16x8*)(&Vb[0][w * 4 + i][lane][0]) = vr[0][i];
#pragma unroll
    for (int i = 0; i < 4; i++) vr[1][i] = ldV(w * 4 + i, 1);
#pragma unroll
    for (int i = 0; i < 4; i++) vr[0][i] = ldV(w * 4 + i, 2);
#pragma unroll
    for (int f = 0; f < 8; f++) kr[f] = ldK(f, 0);
    __syncthreads();

    auto tile_body = [&](int t, int cur, int nxt) {
        // S^T = K @ Q^T, C-layout; K operands straight from global regs.
        f32x16 s0 = mfma32(kr[0], qf[0], zz);
        f32x16 s1 = mfma32(kr[1], qf[0], zz);
#pragma unroll
        for (int ks = 1; ks < 4; ks++) {
            s0 = mfma32(kr[ks * 2 + 0], qf[ks], s0);
            s1 = mfma32(kr[ks * 2 + 1], qf[ks], s1);
        }
        if (t < 31) {
#pragma unroll
            for (int f = 0; f < 8; f++) kr[f] = ldK(f, t + 1);
        }

        // half 0: exp2 -> P frags (natural order, PI-matched) -> PV + row-sum
#pragma unroll
        for (int r = 0; r < 16; r++) s0[r] = __builtin_amdgcn_exp2f(s0[r]);
        {
            bf16x8 pf0, pf1;
#pragma unroll
            for (int u = 0; u < 8; u++) { pf0[u] = (bf16)s0[u]; pf1[u] = (bf16)s0[8 + u]; }
            o0   = mfma32(pf0, *(const bf16x8*)(&Vb[cur][0][lane][0]), o0);
            o1   = mfma32(pf0, *(const bf16x8*)(&Vb[cur][1][lane][0]), o1);
            lacc = mfma32(pf0, ones, lacc);
            o0   = mfma32(pf1, *(const bf16x8*)(&Vb[cur][2][lane][0]), o0);
            o1   = mfma32(pf1, *(const bf16x8*)(&Vb[cur][3][lane][0]), o1);
            lacc = mfma32(pf1, ones, lacc);
        }
        // half 1
#pragma unroll
        for (int r = 0; r < 16; r++) s1[r] = __builtin_amdgcn_exp2f(s1[r]);
        {
            bf16x8 pf2, pf3;
#pragma unroll
            for (int u = 0; u < 8; u++) { pf2[u] = (bf16)s1[u]; pf3[u] = (bf16)s1[8 + u]; }
            o0   = mfma32(pf2, *(const bf16x8*)(&Vb[cur][4][lane][0]), o0);
            o1   = mfma32(pf2, *(const bf16x8*)(&Vb[cur][5][lane][0]), o1);
            lacc = mfma32(pf2, ones, lacc);
            o0   = mfma32(pf3, *(const bf16x8*)(&Vb[cur][6][lane][0]), o0);
            o1   = mfma32(pf3, *(const bf16x8*)(&Vb[cur][7][lane][0]), o1);
            lacc = mfma32(pf3, ones, lacc);
        }

        if (t < 31) {
            // store tile t+1 (loaded 2 tiles ago), then refill with tile t+3
#pragma unroll
            for (int i = 0; i < 4; i++)
                *(bf16x8*)(&Vb[1 - cur][w * 4 + i][lane][0]) = vr[nxt][i];
            const int tn = (t + 3 < 32) ? t + 3 : 31;
#pragma unroll
            for (int i = 0; i < 4; i++) vr[nxt][i] = ldV(w * 4 + i, tn);
            __syncthreads();
        }
    };

    for (int tt = 0; tt < 16; tt++) {
        tile_body(2 * tt + 0, 0, 1);
        tile_body(2 * tt + 1, 1, 0);
    }

    // Epilogue: lacc rows carry this lane's q-row sums (all n-cols identical).
    const int b = bh >> 3, h = bh & 7;
#pragma unroll
    for (int r = 0; r < 16; r++) {
        const int rl = (r & 3) + 8 * (r >> 2) + 4 * hi;
        const float inv = 1.0f / lacc[r];
        const int m = b * L_ + qb + rl;
        const int c0 = h * HD_ + l31;
        Op[((size_t)(c0 >> 3) * M_ + m) * 8 + (c0 & 7)] = (bf16)(o0[r] * inv);
        const int c1 = c0 + 32;
        Op[((size_t)(c1 >> 3) * M_ + m) * 8 + (c1 & 7)] = (bf16)(o1[r] * inv);
    }
}

extern "C" void kernel_launch(void* const* d_in, const int* in_sizes, int n_in,
                              void* d_out, int out_size, void* d_ws, size_t ws_size,
                              hipStream_t stream)
{
    (void)in_sizes; (void)n_in; (void)out_size; (void)ws_size;
    const float* q  = (const float*)d_in[0];
    const float* k  = (const float*)d_in[1];
    const float* v  = (const float*)d_in[2];
    const float* Wq = (const float*)d_in[3];
    const float* bq = (const float*)d_in[4];
    const float* Wk = (const float*)d_in[5];
    const float* bk = (const float*)d_in[6];
    const float* Wv = (const float*)d_in[7];
    const float* bv = (const float*)d_in[8];
    const float* Wo = (const float*)d_in[9];
    const float* bo = (const float*)d_in[10];
    float* out = (float*)d_out;

    // ws (16 MB): Vp @0, Opb @8M.  Wp eliminated -- weights are packed on
    // the fly inside the proj kernels.
    // d_out (16 MB): qh @0, Kp @8M -- dead before the final projection,
    // which overwrites d_out with the fp32 result.
    char* ws = (char*)d_ws;
    const size_t MB = 1024 * 1024;
    bf16* Vp  = (bf16*)(ws);
    bf16* Opb = (bf16*)(ws + 8 * MB);
    bf16* qh  = (bf16*)(d_out);
    bf16* Kp  = (bf16*)((char*)d_out + 8 * MB);

    const float SCALE_LOG2E = 0.06377946282349575f;  // (1/sqrt(512))*log2(e)

    PJob jq{nullptr, q, Wq, bq, qh, SCALE_LOG2E, 0};
    PJob jk{nullptr, k, Wk, bk, Kp, 1.0f, 1};
    PJob jv{nullptr, v, Wv, bv, Vp, 1.0f, 3};
    proj_qkv_kernel<<<dim3(64, 4, 3), dim3(256), 0, stream>>>(jq, jk, jv);

    attn_kernel<<<dim3(32, 32), dim3(128), 0, stream>>>(qh, Kp, Vp, Opb);

    PJob jo{Opb, nullptr, Wo, bo, out, 1.0f, 2};
    proj_o_kernel<<<dim3(64, 8), dim3(256), 0, stream>>>(jo);
}

// Round 15
// 190.853 us; speedup vs baseline: 1.0394x; 1.0394x over previous
//
#include <hip/hip_runtime.h>
#include <hip/hip_bf16.h>

#define B_  4
#define L_  2048
#define D_  512
#define H_  8
#define HD_ 64
#define M_  (B_ * L_)   // 8192

typedef __bf16 bf16;
typedef __attribute__((ext_vector_type(8)))  __bf16 bf16x8;
typedef __attribute__((ext_vector_type(4)))  __bf16 bf16x4;
typedef __attribute__((ext_vector_type(16))) float  f32x16;

__device__ __forceinline__ f32x16 mfma32(bf16x8 a, bf16x8 b, f32x16 c) {
    return __builtin_amdgcn_mfma_f32_32x32x16_bf16(a, b, c, 0, 0, 0);
}

// ---- pack: src fp32 [R][512] -> dst bf16 panels [64][R][8] ----
__device__ __forceinline__ void pack_body(const float* __restrict__ src,
                                          bf16* __restrict__ dst, int R,
                                          int m0, int k0)
{
    __shared__ __align__(16) bf16 tile[64][76];
    const int t = threadIdx.x;
#pragma unroll
    for (int rep = 0; rep < 4; rep++) {
        const int idx = rep * 256 + t;
        const int r = idx >> 4, c4 = idx & 15;
        const float4 f = *(const float4*)(src + (size_t)(m0 + r) * 512 + k0 + c4 * 4);
        bf16x4 v; v[0] = (bf16)f.x; v[1] = (bf16)f.y; v[2] = (bf16)f.z; v[3] = (bf16)f.w;
        *(bf16x4*)(&tile[r][c4 * 4]) = v;
    }
    __syncthreads();
#pragma unroll
    for (int rep = 0; rep < 2; rep++) {
        const int s = rep * 256 + t;
        const int ml = s & 63, kpl = s >> 6;
        const bf16x4 lo = *(const bf16x4*)(&tile[ml][kpl * 8]);
        const bf16x4 hi4 = *(const bf16x4*)(&tile[ml][kpl * 8 + 4]);
        bf16x8 v;
#pragma unroll
        for (int e = 0; e < 4; e++) { v[e] = lo[e]; v[e + 4] = hi4[e]; }
        *(bf16x8*)(dst + ((size_t)(k0 / 8 + kpl) * R + m0 + ml) * 8) = v;
    }
}

// Weights ONLY -- q/k/v transpose is fused into proj_qkv.  R14 proved
// fusing the WEIGHT pack into the projs is a net loss (+10us kernel time
// for -4us launch: fp32 B reads double traffic, and the extra cvt+ds_write
// sits on the drain-limited critical path).  Pack once, read bf16 forever.
// grid (8, 8, 4), block 256.
__global__ __launch_bounds__(256) void pack_w(
    const float* __restrict__ W0, const float* __restrict__ W1,
    const float* __restrict__ W2, const float* __restrict__ W3,
    bf16* __restrict__ Wp)
{
    const int z = blockIdx.z;
    const float* src = z == 0 ? W0 : z == 1 ? W1 : z == 2 ? W2 : W3;
    pack_body(src, Wp + (size_t)z * 64 * 512 * 8, 512, blockIdx.x * 64, blockIdx.y * 64);
}

// ---- projections: relu(X @ W^T + b) (*postmul) ----
// R13 configuration == measured session best (191.5us).
// proj_qkv: 128x128 tile, k-step 32, fused fp32-A transpose, counted-vmcnt
// barrier, 768 blocks = 3/CU.  proj_o: 128x64, k-step 64, 3-deep panel
// prefetch, __syncthreads, 512 blocks = 2/CU.
// Output modes: 0 bf16 [B,H,L,HD]; 1 K-panels [BH][8][L][8]; 2 fp32
// [M,512]; 3 V-panels [BH][256][64][8] PI-swizzled.
struct PJob {
    const bf16* X; const float* Xf; const bf16* W; const float* bias;
    void* out; float postmul; int mode;
};

__device__ __forceinline__ void barrier_lds_only()
{
    // Drain LDS ops so other waves see our ds_writes, but leave global
    // loads (vmcnt) in flight across the barrier.
    asm volatile("s_waitcnt lgkmcnt(0)" ::: "memory");
    __builtin_amdgcn_s_barrier();
}

__device__ __forceinline__ void proj_epilogue_elem(const PJob& jb, int row,
                                                   int col, float v)
{
    const int mode = jb.mode;
    if (mode == 2) {
        ((float*)jb.out)[(size_t)row * D_ + col] = v;
    } else {
        v *= jb.postmul;
        const int b = row >> 11, l = row & (L_ - 1);
        const int h = col >> 6,  hd = col & (HD_ - 1);
        const int bh = b * H_ + h;
        size_t idx;
        if (mode == 0) {
            idx = ((size_t)bh * L_ + l) * HD_ + hd;
        } else if (mode == 1) {       // K panels [bh][hd>>3][l][hd&7]
            idx = (((size_t)bh * 8 + (hd >> 3)) * L_ + l) * 8 + (hd & 7);
        } else {                      // mode 3: V panels, PI-swizzled j
            const int swzl = (l & ~15) | (l & 3) | ((l & 4) << 1) | ((l & 8) >> 1);
            idx = (((size_t)bh * 256 + (swzl >> 3)) * 64 + hd) * 8 + (swzl & 7);
        }
        ((bf16*)jb.out)[idx] = (bf16)v;
    }
}

// qkv: 128x128 tile, k-step 32, fused fp32-A transpose, counted-vmcnt
// barrier.  grid (64, 4, 3) = 768 blocks = 3/CU (all resident).
__global__ __launch_bounds__(256, 3) void proj_qkv_kernel(PJob j0, PJob j1, PJob j2)
{
    const PJob jb = (blockIdx.z == 0) ? j0 : (blockIdx.z == 1) ? j1 : j2;
    const int w    = threadIdx.x >> 6;
    const int lane = threadIdx.x & 63;
    const int l31  = lane & 31;
    const int hi   = lane >> 5;
    const int m0 = blockIdx.x * 128;
    const int n0 = blockIdx.y * 128;
    const int mh = w & 1;
    const int nh = w >> 1;

    __shared__ __align__(16) bf16 Ab[2][8][64][8];   // 2 x 8 KB
    __shared__ __align__(16) bf16 Bb[2][8][64][8];   // 2 x 8 KB

    f32x16 acc[2][2];
#pragma unroll
    for (int mi = 0; mi < 2; mi++)
#pragma unroll
        for (int ni = 0; ni < 2; ni++)
#pragma unroll
            for (int r = 0; r < 16; r++) acc[mi][ni][r] = 0.0f;

    auto ldB = [&](int f, int k0) -> bf16x8 {
        return *(const bf16x8*)(jb.W + ((size_t)((k0 >> 3) + (f >> 2) * 2 + hi) * 512
                                        + n0 + (f & 3) * 32 + l31) * 8);
    };

    bf16x8 rB[2][2];
    float4 rT[2][4];

    auto ldT = [&](int s, int k0) {             // fp32 A: 4 float4/thread
#pragma unroll
        for (int rep = 0; rep < 4; rep++) {
            const int idx = rep * 256 + (int)threadIdx.x;
            rT[s][rep] = *(const float4*)(jb.Xf + (size_t)(m0 + (idx >> 3)) * 512
                                          + k0 + (idx & 7) * 4);
        }
    };
    auto stA = [&](int s, int buf) {            // convert + direct panel write
#pragma unroll
        for (int rep = 0; rep < 4; rep++) {
            const int idx = rep * 256 + (int)threadIdx.x;
            const int r = idx >> 3, c4 = idx & 7;
            const float4 f = rT[s][rep];
            bf16x4 v; v[0] = (bf16)f.x; v[1] = (bf16)f.y;
            v[2] = (bf16)f.z; v[3] = (bf16)f.w;
            const int fs = ((c4 >> 2) << 2) | (r >> 5);
            const int ln = (r & 31) | (((c4 >> 1) & 1) << 5);
            *(bf16x4*)(&Ab[buf][fs][ln][(c4 & 1) * 4]) = v;
        }
    };

    // prologue: k0 -> LDS0; k32 -> set1; k64 -> set0.
    ldT(0, 0); stA(0, 0); ldT(1, 32); ldT(0, 64);
#pragma unroll
    for (int i = 0; i < 2; i++) rB[0][i] = ldB(w * 2 + i, 0);
#pragma unroll
    for (int i = 0; i < 2; i++)
        *(bf16x8*)(&Bb[0][w * 2 + i][lane][0]) = rB[0][i];
#pragma unroll
    for (int i = 0; i < 2; i++) rB[1][i] = ldB(w * 2 + i, 32);
#pragma unroll
    for (int i = 0; i < 2; i++) rB[0][i] = ldB(w * 2 + i, 64);
    __syncthreads();

#pragma unroll
    for (int it = 0; it < 16; it++) {
        const int cur = it & 1;
#pragma unroll
        for (int ks = 0; ks < 2; ks++) {
            const bf16x8 a0 = *(const bf16x8*)(&Ab[cur][ks * 4 + mh * 2 + 0][lane][0]);
            const bf16x8 a1 = *(const bf16x8*)(&Ab[cur][ks * 4 + mh * 2 + 1][lane][0]);
            const bf16x8 b0 = *(const bf16x8*)(&Bb[cur][ks * 4 + nh * 2 + 0][lane][0]);
            const bf16x8 b1 = *(const bf16x8*)(&Bb[cur][ks * 4 + nh * 2 + 1][lane][0]);
            acc[0][0] = mfma32(a0, b0, acc[0][0]);
            acc[0][1] = mfma32(a0, b1, acc[0][1]);
            acc[1][0] = mfma32(a1, b0, acc[1][0]);
            acc[1][1] = mfma32(a1, b1, acc[1][1]);
        }
        if (it < 15) {
            const int s = (it + 1) & 1;          // set holding k_{it+1}
            stA(s, 1 - cur);
#pragma unroll
            for (int i = 0; i < 2; i++)
                *(bf16x8*)(&Bb[1 - cur][w * 2 + i][lane][0]) = rB[s][i];
            if (it < 13) {                       // refill set with k_{it+3}
                ldT(s, (it + 3) * 32);
#pragma unroll
                for (int i = 0; i < 2; i++)
                    rB[s][i] = ldB(w * 2 + i, (it + 3) * 32);
            }
            barrier_lds_only();                  // counted vmcnt rides
        }
    }

#pragma unroll
    for (int ni = 0; ni < 2; ni++) {
        const int col = n0 + (nh * 2 + ni) * 32 + l31;
        const float bn = jb.bias[col];
#pragma unroll
        for (int mi = 0; mi < 2; mi++)
#pragma unroll
            for (int r = 0; r < 16; r++) {
                const int row = m0 + (mh * 2 + mi) * 32 + (r & 3) + 8 * (r >> 2) + 4 * hi;
                proj_epilogue_elem(jb, row, col, fmaxf(acc[mi][ni][r] + bn, 0.0f));
            }
    }
}

// o-proj: R0-R6 structure -- 128x64 tile, k-step 64, 48 KB LDS, 3-deep
// register prefetch, __syncthreads.  grid (64, 8) = 512 blocks = 2/CU
// co-resident (LDS cap 3/CU), so barrier drains overlap across blocks.
__global__ __launch_bounds__(256, 3) void proj_o_kernel(PJob jb)
{
    const int w    = threadIdx.x >> 6;
    const int lane = threadIdx.x & 63;
    const int l31  = lane & 31;
    const int hi   = lane >> 5;
    const int m0 = blockIdx.x * 128;
    const int n0 = blockIdx.y * 64;
    const int mh = w & 1;
    const int nh = w >> 1;

    __shared__ __align__(16) bf16 Ab[2][16][64][8];   // 32 KB
    __shared__ __align__(16) bf16 Bb[2][8][64][8];    // 16 KB

    f32x16 acc[2];
#pragma unroll
    for (int mi = 0; mi < 2; mi++)
#pragma unroll
        for (int r = 0; r < 16; r++) acc[mi][r] = 0.0f;

    auto ldA = [&](int f, int k0) -> bf16x8 {
        return *(const bf16x8*)(jb.X + ((size_t)((k0 >> 3) + (f >> 2) * 2 + hi) * M_
                                        + m0 + (f & 3) * 32 + l31) * 8);
    };
    auto ldB = [&](int f, int k0) -> bf16x8 {
        return *(const bf16x8*)(jb.W + ((size_t)((k0 >> 3) + (f >> 1) * 2 + hi) * 512
                                        + n0 + (f & 1) * 32 + l31) * 8);
    };

    bf16x8 rA[3][4], rB[3][2];
#pragma unroll
    for (int i = 0; i < 4; i++) rA[0][i] = ldA(w * 4 + i, 0);
#pragma unroll
    for (int i = 0; i < 2; i++) rB[0][i] = ldB(w * 2 + i, 0);
#pragma unroll
    for (int i = 0; i < 4; i++) *(bf16x8*)(&Ab[0][w * 4 + i][lane][0]) = rA[0][i];
#pragma unroll
    for (int i = 0; i < 2; i++) *(bf16x8*)(&Bb[0][w * 2 + i][lane][0]) = rB[0][i];
#pragma unroll
    for (int s = 1; s < 3; s++) {
#pragma unroll
        for (int i = 0; i < 4; i++) rA[s][i] = ldA(w * 4 + i, s * 64);
#pragma unroll
        for (int i = 0; i < 2; i++) rB[s][i] = ldB(w * 2 + i, s * 64);
    }
    __syncthreads();

#pragma unroll
    for (int it = 0; it < 8; it++) {
        const int cur = it & 1;
        if (it < 5) {
            const int s = it % 3, kn = (it + 3) * 64;
#pragma unroll
            for (int i = 0; i < 4; i++) rA[s][i] = ldA(w * 4 + i, kn);
#pragma unroll
            for (int i = 0; i < 2; i++) rB[s][i] = ldB(w * 2 + i, kn);
        }
#pragma unroll
        for (int ks = 0; ks < 4; ks++) {
            const bf16x8 bfr = *(const bf16x8*)(&Bb[cur][ks * 2 + nh][lane][0]);
#pragma unroll
            for (int mi = 0; mi < 2; mi++) {
                const bf16x8 afr = *(const bf16x8*)(&Ab[cur][ks * 4 + mh * 2 + mi][lane][0]);
                acc[mi] = mfma32(afr, bfr, acc[mi]);
            }
        }
        if (it < 7) {
            const int s = (it + 1) % 3;
#pragma unroll
            for (int i = 0; i < 4; i++) *(bf16x8*)(&Ab[1 - cur][w * 4 + i][lane][0]) = rA[s][i];
#pragma unroll
            for (int i = 0; i < 2; i++) *(bf16x8*)(&Bb[1 - cur][w * 2 + i][lane][0]) = rB[s][i];
            __syncthreads();
        }
    }

    const int col = n0 + nh * 32 + l31;
    const float bn = jb.bias[col];
#pragma unroll
    for (int mi = 0; mi < 2; mi++)
#pragma unroll
        for (int r = 0; r < 16; r++) {
            const int row = m0 + (mh * 2 + mi) * 32 + (r & 3) + 8 * (r >> 2) + 4 * hi;
            proj_epilogue_elem(jb, row, col, fmaxf(acc[mi][r] + bn, 0.0f));
        }
}

// ---- flash attention, max-free (post-ReLU q,k => scores >= 0) ----
// EXACT round-0 structure + XCD-chunked swizzle (R7-R14: 48.1-49.4 us,
// 100 VGPR, FETCH 12.3 MB).  DO NOT TOUCH: rounds 2-5 proved every TLP/ILP
// restructuring crosses a register-class boundary and spills; R1 proved
// removing its barrier does NOT help (loads are L2-hot; V-sharing wins).
__global__ __launch_bounds__(128, 2) void attn_kernel(
    const bf16* __restrict__ qh, const bf16* __restrict__ Kp,
    const bf16* __restrict__ Vp, bf16* __restrict__ Op)
{
    const int w    = threadIdx.x >> 6;   // 0..1
    const int lane = threadIdx.x & 63;
    const int l31  = lane & 31;
    const int hi   = lane >> 5;

    const int lin  = blockIdx.x + (blockIdx.y << 5);   // grid (32,32)
    const int xcd  = lin & 7;
    const int slot = lin >> 3;                          // 0..127 within XCD
    const int bh   = (xcd << 2) + (slot >> 5);          // 4 bh per XCD
    const int qb   = (slot & 31) * 64 + w * 32;

    const bf16* Q   = qh + (size_t)bh * L_ * HD_;
    const bf16* Kpb = Kp + (size_t)bh * 8 * L_ * 8;
    const bf16* Vpb = Vp + (size_t)bh * 256 * 64 * 8;

    __shared__ __align__(16) bf16 Vb[2][8][64][8];   // 16 KB

    bf16x8 qf[4];
#pragma unroll
    for (int ks = 0; ks < 4; ks++)
        qf[ks] = *(const bf16x8*)(Q + (size_t)(qb + l31) * HD_ + ks * 16 + hi * 8);

    f32x16 zz;
#pragma unroll
    for (int r = 0; r < 16; r++) zz[r] = 0.0f;
    f32x16 o0 = zz, o1 = zz, lacc = zz;
    bf16x8 ones;
#pragma unroll
    for (int u = 0; u < 8; u++) ones[u] = (bf16)1.0f;

    auto ldK = [&](int f, int t) -> bf16x8 {   // f: ks=f>>1, jt=f&1
        return *(const bf16x8*)(Kpb + ((size_t)((f >> 1) * 2 + hi) * L_
                                       + t * 64 + (f & 1) * 32 + l31) * 8);
    };
    auto ldV = [&](int f, int t) -> bf16x8 {   // f: ksj=f>>1, hdf=f&1
        return *(const bf16x8*)(Vpb + ((size_t)(t * 8 + (f >> 1) * 2 + hi) * 64
                                       + (f & 1) * 32 + l31) * 8);
    };

    bf16x8 kr[8], vr[2][4];
#pragma unroll
    for (int i = 0; i < 4; i++) vr[0][i] = ldV(w * 4 + i, 0);
#pragma unroll
    for (int i = 0; i < 4; i++) *(bf16x8*)(&Vb[0][w * 4 + i][lane][0]) = vr[0][i];
#pragma unroll
    for (int i = 0; i < 4; i++) vr[1][i] = ldV(w * 4 + i, 1);
#pragma unroll
    for (int i = 0; i < 4; i++) vr[0][i] = ldV(w * 4 + i, 2);
#pragma unroll
    for (int f = 0; f < 8; f++) kr[f] = ldK(f, 0);
    __syncthreads();

    auto tile_body = [&](int t, int cur, int nxt) {
        // S^T = K @ Q^T, C-layout; K operands straight from global regs.
        f32x16 s0 = mfma32(kr[0], qf[0], zz);
        f32x16 s1 = mfma32(kr[1], qf[0], zz);
#pragma unroll
        for (int ks = 1; ks < 4; ks++) {
            s0 = mfma32(kr[ks * 2 + 0], qf[ks], s0);
            s1 = mfma32(kr[ks * 2 + 1], qf[ks], s1);
        }
        if (t < 31) {
#pragma unroll
            for (int f = 0; f < 8; f++) kr[f] = ldK(f, t + 1);
        }

        // half 0: exp2 -> P frags (natural order, PI-matched) -> PV + row-sum
#pragma unroll
        for (int r = 0; r < 16; r++) s0[r] = __builtin_amdgcn_exp2f(s0[r]);
        {
            bf16x8 pf0, pf1;
#pragma unroll
            for (int u = 0; u < 8; u++) { pf0[u] = (bf16)s0[u]; pf1[u] = (bf16)s0[8 + u]; }
            o0   = mfma32(pf0, *(const bf16x8*)(&Vb[cur][0][lane][0]), o0);
            o1   = mfma32(pf0, *(const bf16x8*)(&Vb[cur][1][lane][0]), o1);
            lacc = mfma32(pf0, ones, lacc);
            o0   = mfma32(pf1, *(const bf16x8*)(&Vb[cur][2][lane][0]), o0);
            o1   = mfma32(pf1, *(const bf16x8*)(&Vb[cur][3][lane][0]), o1);
            lacc = mfma32(pf1, ones, lacc);
        }
        // half 1
#pragma unroll
        for (int r = 0; r < 16; r++) s1[r] = __builtin_amdgcn_exp2f(s1[r]);
        {
            bf16x8 pf2, pf3;
#pragma unroll
            for (int u = 0; u < 8; u++) { pf2[u] = (bf16)s1[u]; pf3[u] = (bf16)s1[8 + u]; }
            o0   = mfma32(pf2, *(const bf16x8*)(&Vb[cur][4][lane][0]), o0);
            o1   = mfma32(pf2, *(const bf16x8*)(&Vb[cur][5][lane][0]), o1);
            lacc = mfma32(pf2, ones, lacc);
            o0   = mfma32(pf3, *(const bf16x8*)(&Vb[cur][6][lane][0]), o0);
            o1   = mfma32(pf3, *(const bf16x8*)(&Vb[cur][7][lane][0]), o1);
            lacc = mfma32(pf3, ones, lacc);
        }

        if (t < 31) {
            // store tile t+1 (loaded 2 tiles ago), then refill with tile t+3
#pragma unroll
            for (int i = 0; i < 4; i++)
                *(bf16x8*)(&Vb[1 - cur][w * 4 + i][lane][0]) = vr[nxt][i];
            const int tn = (t + 3 < 32) ? t + 3 : 31;
#pragma unroll
            for (int i = 0; i < 4; i++) vr[nxt][i] = ldV(w * 4 + i, tn);
            __syncthreads();
        }
    };

    for (int tt = 0; tt < 16; tt++) {
        tile_body(2 * tt + 0, 0, 1);
        tile_body(2 * tt + 1, 1, 0);
    }

    // Epilogue: lacc rows carry this lane's q-row sums (all n-cols identical).
    const int b = bh >> 3, h = bh & 7;
#pragma unroll
    for (int r = 0; r < 16; r++) {
        const int rl = (r & 3) + 8 * (r >> 2) + 4 * hi;
        const float inv = 1.0f / lacc[r];
        const int m = b * L_ + qb + rl;
        const int c0 = h * HD_ + l31;
        Op[((size_t)(c0 >> 3) * M_ + m) * 8 + (c0 & 7)] = (bf16)(o0[r] * inv);
        const int c1 = c0 + 32;
        Op[((size_t)(c1 >> 3) * M_ + m) * 8 + (c1 & 7)] = (bf16)(o1[r] * inv);
    }
}

extern "C" void kernel_launch(void* const* d_in, const int* in_sizes, int n_in,
                              void* d_out, int out_size, void* d_ws, size_t ws_size,
                              hipStream_t stream)
{
    (void)in_sizes; (void)n_in; (void)out_size; (void)ws_size;
    const float* q  = (const float*)d_in[0];
    const float* k  = (const float*)d_in[1];
    const float* v  = (const float*)d_in[2];
    const float* Wq = (const float*)d_in[3];
    const float* bq = (const float*)d_in[4];
    const float* Wk = (const float*)d_in[5];
    const float* bk = (const float*)d_in[6];
    const float* Wv = (const float*)d_in[7];
    const float* bv = (const float*)d_in[8];
    const float* Wo = (const float*)d_in[9];
    const float* bo = (const float*)d_in[10];
    float* out = (float*)d_out;

    // ws (18 MB): Vp @0, Opb @8M, Wp @16M.
    // d_out (16 MB): qh @0, Kp @8M -- dead before the final projection,
    // which overwrites d_out with the fp32 result.
    char* ws = (char*)d_ws;
    const size_t MB = 1024 * 1024;
    bf16* Vp  = (bf16*)(ws);
    bf16* Opb = (bf16*)(ws + 8 * MB);
    bf16* Wp  = (bf16*)(ws + 16 * MB);
    bf16* qh  = (bf16*)(d_out);
    bf16* Kp  = (bf16*)((char*)d_out + 8 * MB);

    bf16* Wqp = Wp;
    bf16* Wkp = Wp + (size_t)64 * 512 * 8;
    bf16* Wvp = Wp + (size_t)2 * 64 * 512 * 8;
    bf16* Wop = Wp + (size_t)3 * 64 * 512 * 8;

    const float SCALE_LOG2E = 0.06377946282349575f;  // (1/sqrt(512))*log2(e)

    pack_w<<<dim3(8, 8, 4), dim3(256), 0, stream>>>(Wq, Wk, Wv, Wo, Wp);

    PJob jq{nullptr, q, Wqp, bq, qh, SCALE_LOG2E, 0};
    PJob jk{nullptr, k, Wkp, bk, Kp, 1.0f, 1};
    PJob jv{nullptr, v, Wvp, bv, Vp, 1.0f, 3};
    proj_qkv_kernel<<<dim3(64, 4, 3), dim3(256), 0, stream>>>(jq, jk, jv);

    attn_kernel<<<dim3(32, 32), dim3(128), 0, stream>>>(qh, Kp, Vp, Opb);

    PJob jo{Opb, nullptr, Wop, bo, out, 1.0f, 2};
    proj_o_kernel<<<dim3(64, 8), dim3(256), 0, stream>>>(jo);
}